// Round 8
// baseline (50.204 us; speedup 1.0000x reference)
//
#include <hip/hip_runtime.h>
#include <hip/hip_fp16.h>

// Problem constants (from reference setup_inputs)
constexpr int BAG       = 40;
constexpr int D         = 768;
constexpr int VOCAB     = 1276;
constexpr int AGE_DEPTH = 91;
constexpr int WROWS     = VOCAB + AGE_DEPTH;   // 1367

constexpr int CPB  = 32;            // columns per block: 16 via LDS + 16 via L2
constexpr int NSLC = D / CPB;       // 24 column slices
constexpr int RPB  = 256;           // rows per block (2 lanes per row)
constexpr int TPB  = 512;           // 8 waves
constexpr int LDSU = 2 * WROWS;     // 2734 uint4 = 43,744 B -> 3 blocks/CU

typedef float fx4 __attribute__((ext_vector_type(4)));

__device__ __forceinline__ __half2 u2h(uint u) {
    union { uint u; __half2 h; } v; v.u = u; return v.h;
}
__device__ __forceinline__ ushort f2h(float f) {
    __half h = __float2half(f);     // RNE
    return *reinterpret_cast<ushort*>(&h);
}

// ---------------------------------------------------------------------------
// Pass 1: convert W (f32) -> f16 table in workspace.
// ---------------------------------------------------------------------------
__global__ __launch_bounds__(256) void convert_w_f16(
    const float* __restrict__ W, ushort* __restrict__ Wh, int n)
{
    const int i = (blockIdx.x * 256 + threadIdx.x) * 8;
    if (i + 8 > n) return;
    const float4 a = *reinterpret_cast<const float4*>(W + i);
    const float4 b = *reinterpret_cast<const float4*>(W + i + 4);
    uint4 p;
    p.x = (uint)f2h(a.x) | ((uint)f2h(a.y) << 16);
    p.y = (uint)f2h(a.z) | ((uint)f2h(a.w) << 16);
    p.z = (uint)f2h(b.x) | ((uint)f2h(b.y) << 16);
    p.w = (uint)f2h(b.z) | ((uint)f2h(b.w) << 16);
    *reinterpret_cast<uint4*>(Wh + i) = p;
}

// ---------------------------------------------------------------------------
// Pass 2: hybrid gather. Per 32-col block: cols [c0, c0+16) staged in LDS and
// gathered via the DS pipe; cols [c0+16, c0+32) gathered straight from the
// f16 table via the VMEM pipe. Both streams interleave in 8-deep batches so
// the DS and TA/L2 pipes run concurrently.
// Grid: (32 rowblocks, 24 slices). Block: 512 thr = 256 rows x 2 chunk-lanes.
// ---------------------------------------------------------------------------
__global__ __launch_bounds__(TPB) void embed_hybrid_kernel(
    const int* __restrict__ word,    // [ROWS, BAG]
    const int* __restrict__ age,     // [ROWS]
    const ushort* __restrict__ Wh,   // [WROWS, D] f16
    const float* __restrict__ bias,  // [D]
    float* __restrict__ out)         // [ROWS, D] f32
{
    __shared__ uint4 lds4[LDSU];

    const int rb = blockIdx.x;
    const int c0 = blockIdx.y * CPB;

    const int t     = threadIdx.x;
    const int chunk = t & 1;               // which 8-col chunk
    const int rloc  = t >> 1;              // 0..255
    const int row   = rb * RPB + rloc;

    const int* __restrict__ wrow = word + row * BAG;
    const int aidx = VOCAB + age[row];

    // ---- stage LDS half: Wh[r, c0..c0+16) -> lds4[u*WROWS + r] ----
    for (int s = t; s < LDSU; s += TPB) {
        const int r = s >> 1;
        const int u = s & 1;
        lds4[u * WROWS + r] =
            *reinterpret_cast<const uint4*>(Wh + (size_t)r * D + c0 + u * 8);
    }
    __syncthreads();

    const uint4*  __restrict__ lpL = lds4 + chunk * WROWS;          // LDS base
    const ushort* __restrict__ gpG = Wh + c0 + 16 + chunk * 8;      // L2 base

    __half2 aL0 = u2h(0u), aL1 = u2h(0u), aL2 = u2h(0u), aL3 = u2h(0u);
    __half2 aG0 = u2h(0u), aG1 = u2h(0u), aG2 = u2h(0u), aG3 = u2h(0u);

    #pragma unroll
    for (int jb = 0; jb < BAG; jb += 8) {
        const int4 q0 = *reinterpret_cast<const int4*>(wrow + jb);
        const int4 q1 = *reinterpret_cast<const int4*>(wrow + jb + 4);
        const int id[8] = {q0.x, q0.y, q0.z, q0.w, q1.x, q1.y, q1.z, q1.w};

        // issue 8 global gathers (VMEM pipe, in flight under the LDS work)
        uint4 g[8];
        #pragma unroll
        for (int u = 0; u < 8; ++u)
            g[u] = *reinterpret_cast<const uint4*>(gpG + (size_t)id[u] * D);

        // 8 LDS gathers + adds (DS pipe)
        #pragma unroll
        for (int u = 0; u < 8; ++u) {
            const uint4 l = lpL[id[u]];
            aL0 = __hadd2(aL0, u2h(l.x));
            aL1 = __hadd2(aL1, u2h(l.y));
            aL2 = __hadd2(aL2, u2h(l.z));
            aL3 = __hadd2(aL3, u2h(l.w));
        }

        // consume the global gathers
        #pragma unroll
        for (int u = 0; u < 8; ++u) {
            aG0 = __hadd2(aG0, u2h(g[u].x));
            aG1 = __hadd2(aG1, u2h(g[u].y));
            aG2 = __hadd2(aG2, u2h(g[u].z));
            aG3 = __hadd2(aG3, u2h(g[u].w));
        }
    }

    // age row (41st gather), both halves
    {
        const uint4 g = *reinterpret_cast<const uint4*>(gpG + (size_t)aidx * D);
        const uint4 l = lpL[aidx];
        aL0 = __hadd2(aL0, u2h(l.x));
        aL1 = __hadd2(aL1, u2h(l.y));
        aL2 = __hadd2(aL2, u2h(l.z));
        aL3 = __hadd2(aL3, u2h(l.w));
        aG0 = __hadd2(aG0, u2h(g.x));
        aG1 = __hadd2(aG1, u2h(g.y));
        aG2 = __hadd2(aG2, u2h(g.z));
        aG3 = __hadd2(aG3, u2h(g.w));
    }

    // ---- epilogue: f32 bias add, nontemporal 32B stores ----
    const int cL = c0 + chunk * 8;          // LDS-half columns
    const int cG = c0 + 16 + chunk * 8;     // L2-half columns
    float* opL = out + (size_t)row * D + cL;
    float* opG = out + (size_t)row * D + cG;

    const float4 bL0 = *reinterpret_cast<const float4*>(bias + cL);
    const float4 bL1 = *reinterpret_cast<const float4*>(bias + cL + 4);
    const float4 bG0 = *reinterpret_cast<const float4*>(bias + cG);
    const float4 bG1 = *reinterpret_cast<const float4*>(bias + cG + 4);

    fx4 oL0 = { bL0.x + __low2float(aL0), bL0.y + __high2float(aL0),
                bL0.z + __low2float(aL1), bL0.w + __high2float(aL1) };
    fx4 oL1 = { bL1.x + __low2float(aL2), bL1.y + __high2float(aL2),
                bL1.z + __low2float(aL3), bL1.w + __high2float(aL3) };
    fx4 oG0 = { bG0.x + __low2float(aG0), bG0.y + __high2float(aG0),
                bG0.z + __low2float(aG1), bG0.w + __high2float(aG1) };
    fx4 oG1 = { bG1.x + __low2float(aG2), bG1.y + __high2float(aG2),
                bG1.z + __low2float(aG3), bG1.w + __high2float(aG3) };

    __builtin_nontemporal_store(oL0, reinterpret_cast<fx4*>(opL));
    __builtin_nontemporal_store(oL1, reinterpret_cast<fx4*>(opL + 4));
    __builtin_nontemporal_store(oG0, reinterpret_cast<fx4*>(opG));
    __builtin_nontemporal_store(oG1, reinterpret_cast<fx4*>(opG + 4));
}

// ---------------------------------------------------------------------------
// Fallback (f32 direct gather) if workspace too small or rows not divisible.
// ---------------------------------------------------------------------------
__global__ __launch_bounds__(192) void embedbag_f32_kernel(
    const int* __restrict__ word, const int* __restrict__ age,
    const float* __restrict__ W, const float* __restrict__ bias,
    float* __restrict__ out)
{
    const int row = blockIdx.x;
    const int c   = threadIdx.x * 4;

    float4 acc = *reinterpret_cast<const float4*>(&bias[c]);
    const int* __restrict__ wrow = word + row * BAG;

    #pragma unroll 8
    for (int j = 0; j < BAG; ++j) {
        const int idx = wrow[j];
        const float4 v = *reinterpret_cast<const float4*>(&W[(size_t)idx * D + c]);
        acc.x += v.x; acc.y += v.y; acc.z += v.z; acc.w += v.w;
    }
    {
        const int idx = VOCAB + age[row];
        const float4 v = *reinterpret_cast<const float4*>(&W[(size_t)idx * D + c]);
        acc.x += v.x; acc.y += v.y; acc.z += v.z; acc.w += v.w;
    }
    *reinterpret_cast<float4*>(&out[(size_t)row * D + c]) = acc;
}

extern "C" void kernel_launch(void* const* d_in, const int* in_sizes, int n_in,
                              void* d_out, int out_size, void* d_ws, size_t ws_size,
                              hipStream_t stream) {
    const int* word   = (const int*)d_in[0];   // [B,S,BAG]
    const int* age    = (const int*)d_in[1];   // [B,S]
    const float* W    = (const float*)d_in[2]; // [WROWS, D]
    const float* bias = (const float*)d_in[3]; // [D]
    float* out        = (float*)d_out;         // [B,S,D]

    const int rows = in_sizes[1];              // B*S = 8192

    const size_t need = (size_t)WROWS * D * sizeof(ushort);  // 2.1 MB
    if (rows % RPB == 0 && ws_size >= need) {
        ushort* Wh = (ushort*)d_ws;
        const int n = WROWS * D;
        convert_w_f16<<<(n / 8 + 255) / 256, 256, 0, stream>>>(W, Wh, n);
        dim3 grid(rows / RPB, NSLC);           // (32, 24) = 768 blocks, 3/CU
        embed_hybrid_kernel<<<grid, TPB, 0, stream>>>(
            word, age, (const ushort*)Wh, bias, out);
    } else {
        embedbag_f32_kernel<<<rows, D / 4, 0, stream>>>(word, age, W, bias, out);
    }
}

// Round 9
// 31.624 us; speedup vs baseline: 1.5875x; 1.5875x over previous
//
#include <hip/hip_runtime.h>
#include <hip/hip_fp16.h>

// Problem constants (from reference setup_inputs)
constexpr int BAG       = 40;
constexpr int D         = 768;
constexpr int VOCAB     = 1276;
constexpr int AGE_DEPTH = 91;
constexpr int WROWS     = VOCAB + AGE_DEPTH;   // 1367

constexpr int COLS = 16;            // f16 columns staged per block
constexpr int NSLC = D / COLS;      // 48 column slices
constexpr int RPB  = 256;           // rows per block (2 lanes per row)
constexpr int TPB  = 512;           // 8 waves
constexpr int LDSU = 2 * WROWS;     // 2734 uint4 = 43,744 B -> 3 blocks/CU

typedef float fx4 __attribute__((ext_vector_type(4)));

__device__ __forceinline__ __half2 u2h(uint u) {
    union { uint u; __half2 h; } v; v.u = u; return v.h;
}
__device__ __forceinline__ ushort f2h(float f) {
    __half h = __float2half(f);     // RNE
    return *reinterpret_cast<ushort*>(&h);
}

// ---------------------------------------------------------------------------
// Pass 1: convert W (f32) -> f16 table in workspace (RNE).
// ---------------------------------------------------------------------------
__global__ __launch_bounds__(256) void convert_w_f16(
    const float* __restrict__ W, ushort* __restrict__ Wh, int n)
{
    const int i = (blockIdx.x * 256 + threadIdx.x) * 8;
    if (i + 8 > n) return;
    const float4 a = *reinterpret_cast<const float4*>(W + i);
    const float4 b = *reinterpret_cast<const float4*>(W + i + 4);
    uint4 p;
    p.x = (uint)f2h(a.x) | ((uint)f2h(a.y) << 16);
    p.y = (uint)f2h(a.z) | ((uint)f2h(a.w) << 16);
    p.z = (uint)f2h(b.x) | ((uint)f2h(b.y) << 16);
    p.w = (uint)f2h(b.z) | ((uint)f2h(b.w) << 16);
    *reinterpret_cast<uint4*>(Wh + i) = p;
}

// ---------------------------------------------------------------------------
// Pass 2: stage f16 column-slice into LDS (16B loads, no convert), then
// gather-sum 41 rows/output-row with EXPLICIT 8-deep ds_read batches so ~8
// LDS reads are in flight per wave (R5-R7 did load->add per iter, exposing
// ~120cyc LDS latency with only ~4 in flight; that was the 26.7us floor).
// Grid: (32 rowblocks, 48 slices). Block: 512 thr = 256 rows x 2 chunk-lanes.
// ---------------------------------------------------------------------------
__global__ __launch_bounds__(TPB) void embed_lds_kernel(
    const int* __restrict__ word,    // [ROWS, BAG]
    const int* __restrict__ age,     // [ROWS]
    const ushort* __restrict__ Wh,   // [WROWS, D] f16
    const float* __restrict__ bias,  // [D]
    float* __restrict__ out)         // [ROWS, D] f32
{
    __shared__ uint4 lds4[LDSU];

    const int rb = blockIdx.x;
    const int c0 = blockIdx.y * COLS;

    const int t     = threadIdx.x;
    const int chunk = t & 1;               // which 8-col chunk of the slice
    const int rloc  = t >> 1;              // 0..255
    const int row   = rb * RPB + rloc;

    const int* __restrict__ wrow = word + row * BAG;

    // ---- stage: Wh[r, c0:c0+16) -> lds4[u*WROWS + r], 16B per thread-iter
    for (int s = t; s < LDSU; s += TPB) {
        const int r = s >> 1;
        const int u = s & 1;
        lds4[u * WROWS + r] =
            *reinterpret_cast<const uint4*>(Wh + (size_t)r * D + c0 + u * 8);
    }

    // First index batch + age index issued while staging loads are in flight.
    const int aidx = VOCAB + age[row];
    int cur[8];
    {
        const int4 q0 = *reinterpret_cast<const int4*>(wrow);
        const int4 q1 = *reinterpret_cast<const int4*>(wrow + 4);
        cur[0]=q0.x; cur[1]=q0.y; cur[2]=q0.z; cur[3]=q0.w;
        cur[4]=q1.x; cur[5]=q1.y; cur[6]=q1.z; cur[7]=q1.w;
    }

    __syncthreads();

    const uint4* __restrict__ lp = lds4 + chunk * WROWS;

    __half2 a0 = u2h(0u), a1 = u2h(0u), a2 = u2h(0u), a3 = u2h(0u);

    #pragma unroll
    for (int kb = 0; kb < 5; ++kb) {
        // Issue 8 LDS gathers together (8 in flight on the DS pipe)
        uint4 g[8];
        #pragma unroll
        for (int u = 0; u < 8; ++u)
            g[u] = lp[cur[u]];

        // Prefetch next batch's indices (VMEM latency hides under DS batch)
        int nxt[8];
        if (kb < 4) {
            const int4 q0 = *reinterpret_cast<const int4*>(wrow + 8 * kb + 8);
            const int4 q1 = *reinterpret_cast<const int4*>(wrow + 8 * kb + 12);
            nxt[0]=q0.x; nxt[1]=q0.y; nxt[2]=q0.z; nxt[3]=q0.w;
            nxt[4]=q1.x; nxt[5]=q1.y; nxt[6]=q1.z; nxt[7]=q1.w;
        }

        // Consume
        #pragma unroll
        for (int u = 0; u < 8; ++u) {
            a0 = __hadd2(a0, u2h(g[u].x));
            a1 = __hadd2(a1, u2h(g[u].y));
            a2 = __hadd2(a2, u2h(g[u].z));
            a3 = __hadd2(a3, u2h(g[u].w));
        }

        if (kb < 4) {
            #pragma unroll
            for (int u = 0; u < 8; ++u) cur[u] = nxt[u];
        }
    }

    // Age row (41st gather)
    {
        const uint4 g = lp[aidx];
        a0 = __hadd2(a0, u2h(g.x));
        a1 = __hadd2(a1, u2h(g.y));
        a2 = __hadd2(a2, u2h(g.z));
        a3 = __hadd2(a3, u2h(g.w));
    }

    // ---- epilogue: f32 bias add, nontemporal 32B store ----
    const int c = c0 + chunk * 8;
    const float4 b0 = *reinterpret_cast<const float4*>(bias + c);
    const float4 b1 = *reinterpret_cast<const float4*>(bias + c + 4);
    fx4 o0 = { b0.x + __low2float(a0), b0.y + __high2float(a0),
               b0.z + __low2float(a1), b0.w + __high2float(a1) };
    fx4 o1 = { b1.x + __low2float(a2), b1.y + __high2float(a2),
               b1.z + __low2float(a3), b1.w + __high2float(a3) };
    float* op = out + (size_t)row * D + c;
    __builtin_nontemporal_store(o0, reinterpret_cast<fx4*>(op));
    __builtin_nontemporal_store(o1, reinterpret_cast<fx4*>(op + 4));
}

// ---------------------------------------------------------------------------
// Fallback (f32 direct gather) if workspace too small or rows not divisible.
// ---------------------------------------------------------------------------
__global__ __launch_bounds__(192) void embedbag_f32_kernel(
    const int* __restrict__ word, const int* __restrict__ age,
    const float* __restrict__ W, const float* __restrict__ bias,
    float* __restrict__ out)
{
    const int row = blockIdx.x;
    const int c   = threadIdx.x * 4;

    float4 acc = *reinterpret_cast<const float4*>(&bias[c]);
    const int* __restrict__ wrow = word + row * BAG;

    #pragma unroll 8
    for (int j = 0; j < BAG; ++j) {
        const int idx = wrow[j];
        const float4 v = *reinterpret_cast<const float4*>(&W[(size_t)idx * D + c]);
        acc.x += v.x; acc.y += v.y; acc.z += v.z; acc.w += v.w;
    }
    {
        const int idx = VOCAB + age[row];
        const float4 v = *reinterpret_cast<const float4*>(&W[(size_t)idx * D + c]);
        acc.x += v.x; acc.y += v.y; acc.z += v.z; acc.w += v.w;
    }
    *reinterpret_cast<float4*>(&out[(size_t)row * D + c]) = acc;
}

extern "C" void kernel_launch(void* const* d_in, const int* in_sizes, int n_in,
                              void* d_out, int out_size, void* d_ws, size_t ws_size,
                              hipStream_t stream) {
    const int* word   = (const int*)d_in[0];   // [B,S,BAG]
    const int* age    = (const int*)d_in[1];   // [B,S]
    const float* W    = (const float*)d_in[2]; // [WROWS, D]
    const float* bias = (const float*)d_in[3]; // [D]
    float* out        = (float*)d_out;         // [B,S,D]

    const int rows = in_sizes[1];              // B*S = 8192

    const size_t need = (size_t)WROWS * D * sizeof(ushort);  // 2.1 MB
    if (rows % RPB == 0 && ws_size >= need) {
        ushort* Wh = (ushort*)d_ws;
        const int n = WROWS * D;
        convert_w_f16<<<(n / 8 + 255) / 256, 256, 0, stream>>>(W, Wh, n);
        dim3 grid(rows / RPB, NSLC);           // (32, 48) = 1536 blocks
        embed_lds_kernel<<<grid, TPB, 0, stream>>>(
            word, age, (const ushort*)Wh, bias, out);
    } else {
        embedbag_f32_kernel<<<rows, D / 4, 0, stream>>>(word, age, W, bias, out);
    }
}

// Round 10
// 29.373 us; speedup vs baseline: 1.7092x; 1.0766x over previous
//
#include <hip/hip_runtime.h>
#include <hip/hip_fp16.h>

// Problem constants (from reference setup_inputs)
constexpr int BAG       = 40;
constexpr int D         = 768;
constexpr int VOCAB     = 1276;
constexpr int AGE_DEPTH = 91;
constexpr int WROWS     = VOCAB + AGE_DEPTH;   // 1367

constexpr int ROWS_PB = 256;          // rows per block
constexpr int TPB     = 512;          // 8 waves; 256 rows x 2 chunk-lanes
constexpr int COLS    = 16;           // f16 cols per slice
constexpr int SPB     = 6;            // slices per block -> 96 cols
constexpr int CPB     = COLS * SPB;   // 96
constexpr int NSG     = D / CPB;      // 8 column groups
constexpr int LDSU    = 2 * WROWS;    // 2734 uint4 per buffer (43,744 B)
constexpr int SITER   = (LDSU + TPB - 1) / TPB;   // 6 stage iters/thread

typedef float fx4 __attribute__((ext_vector_type(4)));

__device__ __forceinline__ __half2 u2h(uint u) {
    union { uint u; __half2 h; } v; v.u = u; return v.h;
}
__device__ __forceinline__ ushort f2h(float f) {
    __half h = __float2half(f);     // RNE
    return *reinterpret_cast<ushort*>(&h);
}
__device__ __forceinline__ uint4 pack8(const float4 a, const float4 b) {
    uint4 p;
    p.x = (uint)f2h(a.x) | ((uint)f2h(a.y) << 16);
    p.y = (uint)f2h(a.z) | ((uint)f2h(a.w) << 16);
    p.z = (uint)f2h(b.x) | ((uint)f2h(b.y) << 16);
    p.w = (uint)f2h(b.z) | ((uint)f2h(b.w) << 16);
    return p;
}

// ---------------------------------------------------------------------------
// Persistent-slice block, double-buffered LDS.
// Grid (32, 8) = 256 blocks = 1/CU (LDS 87.5KB forces 1 block/CU).
// Block owns 256 rows x 96 cols: indices register-resident across 6 slices;
// per slice: STAGE_LOAD(next) || GATHER(cur) || store, then cvt+ds_write(next).
// ---------------------------------------------------------------------------
__global__ __launch_bounds__(TPB) void embed_dbuf_kernel(
    const int* __restrict__ word,    // [ROWS, BAG]
    const int* __restrict__ age,     // [ROWS]
    const float* __restrict__ W,     // [WROWS, D] f32
    const float* __restrict__ bias,  // [D]
    float* __restrict__ out)         // [ROWS, D] f32
{
    __shared__ uint4 buf[2][LDSU];

    const int rb  = blockIdx.x;
    const int cb0 = blockIdx.y * CPB;

    const int t     = threadIdx.x;
    const int chunk = t & 1;               // which 8-col chunk of a slice
    const int rloc  = t >> 1;              // 0..255
    const int row   = rb * ROWS_PB + rloc;

    // ---- indices: loaded ONCE, reused across all 6 slices ----
    const int* __restrict__ wrow = word + row * BAG;
    int idx[BAG];
    #pragma unroll
    for (int j = 0; j < BAG; j += 4) {
        const int4 q = *reinterpret_cast<const int4*>(wrow + j);
        idx[j] = q.x; idx[j + 1] = q.y; idx[j + 2] = q.z; idx[j + 3] = q.w;
    }
    const int aidx = VOCAB + age[row];

    // ---- prologue: stage slice 0 into buf[0] (load+cvt+write) ----
    #pragma unroll
    for (int k = 0; k < SITER; ++k) {
        const int i = t + k * TPB;
        if (i < LDSU) {
            const int r = i >> 1, u = i & 1;
            const float* src = W + (size_t)r * D + cb0 + u * 8;
            const float4 a = *reinterpret_cast<const float4*>(src);
            const float4 b = *reinterpret_cast<const float4*>(src + 4);
            buf[0][u * WROWS + r] = pack8(a, b);
        }
    }
    __syncthreads();

    #pragma unroll
    for (int s = 0; s < SPB; ++s) {
        // 1. STAGE_LOAD: issue next slice's f32 loads (latency hides under 2.)
        float4 sa[SITER], sb[SITER];
        if (s + 1 < SPB) {
            const int cbn = cb0 + (s + 1) * COLS;
            #pragma unroll
            for (int k = 0; k < SITER; ++k) {
                const int i = t + k * TPB;
                if (i < LDSU) {
                    const int r = i >> 1, u = i & 1;
                    const float* src = W + (size_t)r * D + cbn + u * 8;
                    sa[k] = *reinterpret_cast<const float4*>(src);
                    sb[k] = *reinterpret_cast<const float4*>(src + 4);
                }
            }
        }

        // 2. GATHER slice s from buf[s&1] (DS pipe, 41 ds_read_b128)
        const uint4* __restrict__ lp = buf[s & 1] + chunk * WROWS;
        __half2 a0 = u2h(0u), a1 = u2h(0u), a2 = u2h(0u), a3 = u2h(0u);
        #pragma unroll
        for (int kb = 0; kb < 5; ++kb) {
            uint4 g[8];
            #pragma unroll
            for (int u = 0; u < 8; ++u)
                g[u] = lp[idx[kb * 8 + u]];
            #pragma unroll
            for (int u = 0; u < 8; ++u) {
                a0 = __hadd2(a0, u2h(g[u].x));
                a1 = __hadd2(a1, u2h(g[u].y));
                a2 = __hadd2(a2, u2h(g[u].z));
                a3 = __hadd2(a3, u2h(g[u].w));
            }
        }
        {
            const uint4 g = lp[aidx];
            a0 = __hadd2(a0, u2h(g.x));
            a1 = __hadd2(a1, u2h(g.y));
            a2 = __hadd2(a2, u2h(g.z));
            a3 = __hadd2(a3, u2h(g.w));
        }

        // 3. epilogue: f32 bias add, nontemporal 32B store
        {
            const int c = cb0 + s * COLS + chunk * 8;
            const float4 b0 = *reinterpret_cast<const float4*>(bias + c);
            const float4 b1 = *reinterpret_cast<const float4*>(bias + c + 4);
            fx4 o0 = { b0.x + __low2float(a0), b0.y + __high2float(a0),
                       b0.z + __low2float(a1), b0.w + __high2float(a1) };
            fx4 o1 = { b1.x + __low2float(a2), b1.y + __high2float(a2),
                       b1.z + __low2float(a3), b1.w + __high2float(a3) };
            float* op = out + (size_t)row * D + c;
            __builtin_nontemporal_store(o0, reinterpret_cast<fx4*>(op));
            __builtin_nontemporal_store(o1, reinterpret_cast<fx4*>(op + 4));
        }

        // 4. STAGE_WRITE: cvt + ds_write next slice into the other buffer
        if (s + 1 < SPB) {
            #pragma unroll
            for (int k = 0; k < SITER; ++k) {
                const int i = t + k * TPB;
                if (i < LDSU) {
                    const int r = i >> 1, u = i & 1;
                    buf[(s + 1) & 1][u * WROWS + r] = pack8(sa[k], sb[k]);
                }
            }
        }
        __syncthreads();
    }
}

// ---------------------------------------------------------------------------
// Fallback (f32 direct gather) if shapes don't divide.
// ---------------------------------------------------------------------------
__global__ __launch_bounds__(192) void embedbag_f32_kernel(
    const int* __restrict__ word, const int* __restrict__ age,
    const float* __restrict__ W, const float* __restrict__ bias,
    float* __restrict__ out)
{
    const int row = blockIdx.x;
    const int c   = threadIdx.x * 4;

    float4 acc = *reinterpret_cast<const float4*>(&bias[c]);
    const int* __restrict__ wrow = word + row * BAG;

    #pragma unroll 8
    for (int j = 0; j < BAG; ++j) {
        const int idx = wrow[j];
        const float4 v = *reinterpret_cast<const float4*>(&W[(size_t)idx * D + c]);
        acc.x += v.x; acc.y += v.y; acc.z += v.z; acc.w += v.w;
    }
    {
        const int idx = VOCAB + age[row];
        const float4 v = *reinterpret_cast<const float4*>(&W[(size_t)idx * D + c]);
        acc.x += v.x; acc.y += v.y; acc.z += v.z; acc.w += v.w;
    }
    *reinterpret_cast<float4*>(&out[(size_t)row * D + c]) = acc;
}

extern "C" void kernel_launch(void* const* d_in, const int* in_sizes, int n_in,
                              void* d_out, int out_size, void* d_ws, size_t ws_size,
                              hipStream_t stream) {
    const int* word   = (const int*)d_in[0];   // [B,S,BAG]
    const int* age    = (const int*)d_in[1];   // [B,S]
    const float* W    = (const float*)d_in[2]; // [WROWS, D]
    const float* bias = (const float*)d_in[3]; // [D]
    float* out        = (float*)d_out;         // [B,S,D]

    const int rows = in_sizes[1];              // B*S = 8192

    if (rows % ROWS_PB == 0) {
        dim3 grid(rows / ROWS_PB, NSG);        // (32, 8) = 256 blocks = 1/CU
        embed_dbuf_kernel<<<grid, TPB, 0, stream>>>(word, age, W, bias, out);
    } else {
        embedbag_f32_kernel<<<rows, D / 4, 0, stream>>>(word, age, W, bias, out);
    }
}